// Round 1
// baseline (80.071 us; speedup 1.0000x reference)
//
#include <hip/hip_runtime.h>

#define NSEG 196
#define BATCH 8
#define IMH 224
#define IMW 224
#define NPIX (IMH * IMW)          // 50176
#define EMB 768
#define ACC_STRIDE 6              // s0..s4 feature sums + count

// ---------------------------------------------------------------------------
// Kernel 1: per-(batch,segment) accumulation of [c0,c1,c2,x,y,count]
// Grid: BATCH * CHUNKS_PER_BATCH blocks, 256 threads.
// Each block owns a contiguous pixel chunk of one batch image; accumulates
// into LDS [196][6] with LDS atomics, then flushes with global atomics.
// ---------------------------------------------------------------------------
#define CHUNKS_PER_BATCH 64

__global__ __launch_bounds__(256)
void spt_accum_kernel(const float* __restrict__ img,
                      const int* __restrict__ seg,
                      float* __restrict__ ws) {
    __shared__ float lacc[NSEG * ACC_STRIDE];

    const int tid = threadIdx.x;
    for (int i = tid; i < NSEG * ACC_STRIDE; i += 256) lacc[i] = 0.0f;
    __syncthreads();

    const int batch = blockIdx.x / CHUNKS_PER_BATCH;
    const int chunk = blockIdx.x % CHUNKS_PER_BATCH;
    const int pix_per_chunk = (NPIX + CHUNKS_PER_BATCH - 1) / CHUNKS_PER_BATCH; // 784
    const int n0 = chunk * pix_per_chunk;
    const int n1 = (n0 + pix_per_chunk < NPIX) ? (n0 + pix_per_chunk) : NPIX;

    const float* __restrict__ imgb = img + (size_t)batch * 3 * NPIX;
    const int*   __restrict__ segb = seg + (size_t)batch * NPIX;

    const float inv223 = 1.0f / 223.0f;

    for (int n = n0 + tid; n < n1; n += 256) {
        const float c0 = imgb[n];
        const float c1 = imgb[NPIX + n];
        const float c2 = imgb[2 * NPIX + n];
        const int   s  = segb[n];
        const int   h  = n / IMW;
        const int   w  = n - h * IMW;
        const float x  = (float)w * inv223;
        const float y  = (float)h * inv223;
        float* p = &lacc[s * ACC_STRIDE];
        atomicAdd(&p[0], c0);
        atomicAdd(&p[1], c1);
        atomicAdd(&p[2], c2);
        atomicAdd(&p[3], x);
        atomicAdd(&p[4], y);
        atomicAdd(&p[5], 1.0f);
    }
    __syncthreads();

    float* __restrict__ wsb = ws + (size_t)batch * NSEG * ACC_STRIDE;
    for (int i = tid; i < NSEG * ACC_STRIDE; i += 256) {
        const float v = lacc[i];
        if (v != 0.0f) atomicAdd(&wsb[i], v);
    }
}

// ---------------------------------------------------------------------------
// Kernel 2: out[bs][e] = (sum_f featsum[f]*W[f][e] + cnt*bias[e]) / max(cnt,1)
// Grid: B*NSEG blocks (=1568), 256 threads, 3 e-values per thread.
// ---------------------------------------------------------------------------
__global__ __launch_bounds__(256)
void spt_project_kernel(const float* __restrict__ ws,
                        const float* __restrict__ Wm,
                        const float* __restrict__ bias,
                        float* __restrict__ out) {
    const int bs = blockIdx.x;     // 0 .. B*NSEG-1
    __shared__ float fs[ACC_STRIDE];
    if (threadIdx.x < ACC_STRIDE) fs[threadIdx.x] = ws[bs * ACC_STRIDE + threadIdx.x];
    __syncthreads();

    const float cnt = fs[5];
    const float inv = 1.0f / fmaxf(cnt, 1.0f);
    const float f0 = fs[0], f1 = fs[1], f2 = fs[2], f3 = fs[3], f4 = fs[4];

    float* __restrict__ outb = out + (size_t)bs * EMB;
    #pragma unroll
    for (int it = 0; it < 3; ++it) {
        const int e = threadIdx.x + it * 256;
        float acc = cnt * bias[e];
        acc += f0 * Wm[0 * EMB + e];
        acc += f1 * Wm[1 * EMB + e];
        acc += f2 * Wm[2 * EMB + e];
        acc += f3 * Wm[3 * EMB + e];
        acc += f4 * Wm[4 * EMB + e];
        outb[e] = acc * inv;
    }
}

extern "C" void kernel_launch(void* const* d_in, const int* in_sizes, int n_in,
                              void* d_out, int out_size, void* d_ws, size_t ws_size,
                              hipStream_t stream) {
    const float* img  = (const float*)d_in[0];   // [8,3,224,224]
    const int*   seg  = (const int*)d_in[1];     // [8,224,224]
    const float* Wm   = (const float*)d_in[2];   // [5,768]
    const float* bias = (const float*)d_in[3];   // [768]
    float* out = (float*)d_out;                  // [8,196,768]
    float* ws  = (float*)d_ws;                   // [8*196*6] accumulators

    // ws is poisoned 0xAA before every call — zero the accumulators.
    hipMemsetAsync(ws, 0, (size_t)BATCH * NSEG * ACC_STRIDE * sizeof(float), stream);

    spt_accum_kernel<<<BATCH * CHUNKS_PER_BATCH, 256, 0, stream>>>(img, seg, ws);
    spt_project_kernel<<<BATCH * NSEG, 256, 0, stream>>>(ws, Wm, bias, out);
}